// Round 3
// baseline (833.455 us; speedup 1.0000x reference)
//
#include <hip/hip_runtime.h>
#include <hip/hip_bf16.h>

// GraphResBlock on MI355X — round 3.
// DTYPES (per reference): all float inputs are fp32 (const float*), edge_index int32,
// output fp32 (float*). Internally: bf16 MFMA with fp32 accumulate/epilogues.
//
// Dataflow (D0/D1 = bf16 scratch carved from d_out's 82MB; Y = bf16 in ws):
//   conv_w:      5 fp32 weights -> Wcat bf16 (ws)
//   gn_elu:      x(f32) -> D0 bf16                    (GN(pre)+ELU)
//   gemm<0>:     D0 -> Y                              (lin1 + GN1 + ELU)
//   gemm<1>:     Y  -> D0 (h1), asrc/adst (fp32 dots) (g1 lin)
//   agg:         D0 -> D1                             (softmax-agg + g1_b + GN2 + ELU)
//   gemm<1>:     D1 -> D0 (h2), asrc/adst
//   agg:         D0 -> Y                              (+ g2_b + GN3 + ELU)
//   gemm<2>:     (Y bf16, x f32-streamed) -> d_out f32 (lin2 + skip, K=512)

typedef __bf16 bf16x8 __attribute__((ext_vector_type(8)));
typedef float floatx4 __attribute__((ext_vector_type(4)));

__device__ __forceinline__ __hip_bfloat16 f2b(float f) { return __float2bfloat16(f); }
__device__ __forceinline__ float b2f(__hip_bfloat16 v) { return __bfloat162float(v); }

__device__ __forceinline__ bf16x8 cvt8(const float* p) {
  float4 a = *(const float4*)p, b = *(const float4*)(p + 4);
  bf16x8 r;
  r[0] = (__bf16)a.x; r[1] = (__bf16)a.y; r[2] = (__bf16)a.z; r[3] = (__bf16)a.w;
  r[4] = (__bf16)b.x; r[5] = (__bf16)b.y; r[6] = (__bf16)b.z; r[7] = (__bf16)b.w;
  return r;
}

// ---------------- weight fp32 -> bf16 pack ----------------
// Wcat layout: [lin1 65536][g1 65536][g2 65536][lin2 131072][skip 131072]
__global__ void conv_w_k(const float* __restrict__ s0, const float* __restrict__ s1,
                         const float* __restrict__ s2, const float* __restrict__ s3,
                         const float* __restrict__ s4, __hip_bfloat16* __restrict__ d) {
  int i = (blockIdx.x * blockDim.x + threadIdx.x) * 4;
  if (i >= 458752) return;
  const float* s; int off;
  if      (i < 65536)  { s = s0; off = 0; }
  else if (i < 131072) { s = s1; off = 65536; }
  else if (i < 196608) { s = s2; off = 131072; }
  else if (i < 327680) { s = s3; off = 196608; }
  else                 { s = s4; off = 327680; }
  float4 v = *(const float4*)(s + (i - off));
  union { ushort4 u; __hip_bfloat16 h[4]; } st;
  st.h[0] = f2b(v.x); st.h[1] = f2b(v.y); st.h[2] = f2b(v.z); st.h[3] = f2b(v.w);
  *(ushort4*)(d + i) = st.u;
}

// ---------------- pre GroupNorm(8) + ELU: fp32 -> bf16 ----------------
__global__ void gn_elu_k(const float* __restrict__ x, const float* __restrict__ w,
                         const float* __restrict__ b, __hip_bfloat16* __restrict__ o, int ng) {
  int g = blockIdx.x * blockDim.x + threadIdx.x;
  if (g >= ng) return;
  int gi = g & 31;                        // group within row (C=256 -> 32 groups)
  size_t basei = (size_t)g * 8;
  float4 u0 = *(const float4*)(x + basei), u1 = *(const float4*)(x + basei + 4);
  float f[8] = {u0.x, u0.y, u0.z, u0.w, u1.x, u1.y, u1.z, u1.w};
  float mu = 0.f;
#pragma unroll
  for (int i = 0; i < 8; i++) mu += f[i];
  mu *= 0.125f;
  float var = 0.f;
#pragma unroll
  for (int i = 0; i < 8; i++) { float d = f[i] - mu; var += d * d; }
  float inv = rsqrtf(var * 0.125f + 1e-5f);
  union { uint4 u; __hip_bfloat16 h[8]; } st;
#pragma unroll
  for (int i = 0; i < 8; i++) {
    float vv = (f[i] - mu) * inv * w[gi * 8 + i] + b[gi * 8 + i];
    vv = (vv > 0.f) ? vv : (__expf(vv) - 1.f);
    st.h[i] = f2b(vv);
  }
  *(uint4*)(o + basei) = st.u;
}

// ---------------- fused MFMA GEMM, block tile = 16 rows x 256 cols ----------------
// MODE 0: outB = ELU(GN(A@W^T + bias)) bf16
// MODE 1: outB = A@W^T bf16; asrc/adst = row-dots with avs/avd (fp32)
// MODE 2: outF = A@W^T + Af32@W2^T + bias + bias2 (fp32 out, Nc=512; Af32 streamed)
template <int MODE>
__global__ __launch_bounds__(256) void gemm_f(
    const __hip_bfloat16* __restrict__ A, const float* __restrict__ Af32,
    const __hip_bfloat16* __restrict__ W, const __hip_bfloat16* __restrict__ W2,
    const float* __restrict__ bias, const float* __restrict__ bias2,
    const float* __restrict__ gnw, const float* __restrict__ gnb,
    const float* __restrict__ avs, const float* __restrict__ avd,
    __hip_bfloat16* __restrict__ outB, float* __restrict__ outF,
    float* __restrict__ asrc, float* __restrict__ adst, int Nc) {
  int wv = threadIdx.x >> 6, lane = threadIdx.x & 63;
  int l16 = lane & 15, quad = lane >> 4;
  int rows0 = blockIdx.y * 16;
  int colw = blockIdx.x * 256 + wv * 64;
  size_t arow = (size_t)(rows0 + l16) * 256 + quad * 8;
  floatx4 acc[4] = {{0.f,0.f,0.f,0.f},{0.f,0.f,0.f,0.f},{0.f,0.f,0.f,0.f},{0.f,0.f,0.f,0.f}};
#pragma unroll
  for (int kt = 0; kt < (MODE == 2 ? 16 : 8); ++kt) {
    bool second = (MODE == 2) && (kt >= 8);
    int kk = second ? (kt - 8) * 32 : kt * 32;
    const __hip_bfloat16* Wb = second ? W2 : W;
    bf16x8 avv;                                     // A[m=l16][k=quad*8+j]
    if (second) avv = cvt8(Af32 + arow + kk);       // stream-convert fp32 x
    else        avv = *(const bf16x8*)(A + arow + kk);
#pragma unroll
    for (int j = 0; j < 4; ++j) {                   // B[k][n]=W[n][k]: n=l16, k=quad*8+j
      bf16x8 bvv = *(const bf16x8*)(Wb + (size_t)(colw + j * 16 + l16) * 256 + kk + quad * 8);
      acc[j] = __builtin_amdgcn_mfma_f32_16x16x32_bf16(avv, bvv, acc[j], 0, 0, 0);
    }
  }
  // C/D: col = colw + j*16 + l16, row = rows0 + quad*4 + i
  if (MODE == 0) {
#pragma unroll
    for (int j = 0; j < 4; ++j) {
      int col = colw + j * 16 + l16;
      float bs = bias[col], gw = gnw[col], gb = gnb[col];
#pragma unroll
      for (int i = 0; i < 4; ++i) {
        float v = acc[j][i] + bs;
        float s = v;                               // GN over 8 cols: lane bits 0..2
        s += __shfl_xor(s, 1, 64); s += __shfl_xor(s, 2, 64); s += __shfl_xor(s, 4, 64);
        float muv = s * 0.125f, d = v - muv;
        float q = d * d;
        q += __shfl_xor(q, 1, 64); q += __shfl_xor(q, 2, 64); q += __shfl_xor(q, 4, 64);
        float r = d * rsqrtf(q * 0.125f + 1e-5f) * gw + gb;
        r = (r > 0.f) ? r : (__expf(r) - 1.f);
        outB[(size_t)(rows0 + quad * 4 + i) * 256 + col] = f2b(r);
      }
    }
  } else if (MODE == 1) {
    __shared__ float sA[4][16], sD[4][16];
    float ps[4] = {0.f,0.f,0.f,0.f}, pd[4] = {0.f,0.f,0.f,0.f};
#pragma unroll
    for (int j = 0; j < 4; ++j) {
      int col = colw + j * 16 + l16;
      float ws = avs[col], wd = avd[col];
#pragma unroll
      for (int i = 0; i < 4; ++i) {
        outB[(size_t)(rows0 + quad * 4 + i) * 256 + col] = f2b(acc[j][i]);
        ps[i] += acc[j][i] * ws;
        pd[i] += acc[j][i] * wd;
      }
    }
#pragma unroll
    for (int i = 0; i < 4; ++i) {
#pragma unroll
      for (int m = 1; m <= 8; m <<= 1) {
        ps[i] += __shfl_xor(ps[i], m, 64);
        pd[i] += __shfl_xor(pd[i], m, 64);
      }
      if (l16 == 0) { sA[wv][quad * 4 + i] = ps[i]; sD[wv][quad * 4 + i] = pd[i]; }
    }
    __syncthreads();
    if (threadIdx.x < 16) {
      int r = threadIdx.x;
      asrc[rows0 + r] = sA[0][r] + sA[1][r] + sA[2][r] + sA[3][r];
      adst[rows0 + r] = sD[0][r] + sD[1][r] + sD[2][r] + sD[3][r];
    }
  } else {
#pragma unroll
    for (int j = 0; j < 4; ++j) {
      int col = colw + j * 16 + l16;
      float bs = bias[col] + bias2[col];
#pragma unroll
      for (int i = 0; i < 4; ++i)
        outF[(size_t)(rows0 + quad * 4 + i) * Nc + col] = acc[j][i] + bs;
    }
  }
}

// ---------------- CSR build (by dst), clamped ----------------
__global__ void zero_k(int* p, int n) {
  int i = blockIdx.x * blockDim.x + threadIdx.x;
  if (i < n) p[i] = 0;
}

__global__ void count_deg_k(const int* __restrict__ ei, int E, int NN, int* __restrict__ counts) {
  int e = blockIdx.x * blockDim.x + threadIdx.x;
  if (e >= E + NN) return;
  int d = (e < E) ? ei[E + e] : (e - E);
  if ((unsigned)d >= (unsigned)NN) d = 0;
  atomicAdd(&counts[d], 1);
}

__global__ void scan_k(const int* __restrict__ counts, int* __restrict__ indptr,
                       int* __restrict__ fill, int NN) {
  __shared__ int wsum[16];
  __shared__ int carry_s;
  __shared__ int ctot;
  int tid = threadIdx.x;
  int lane = tid & 63, wid = tid >> 6;
  if (tid == 0) carry_s = 0;
  __syncthreads();
  for (int base = 0; base < NN; base += 1024) {
    int idx = base + tid;
    int v = (idx < NN) ? counts[idx] : 0;
    int s = v;
#pragma unroll
    for (int off = 1; off < 64; off <<= 1) {
      int t = __shfl_up(s, off, 64);
      if (lane >= off) s += t;
    }
    if (lane == 63) wsum[wid] = s;
    __syncthreads();
    if (tid == 0) {
      int run = 0;
#pragma unroll
      for (int i = 0; i < 16; i++) { int t = wsum[i]; wsum[i] = run; run += t; }
      ctot = run;
    }
    __syncthreads();
    int excl = s - v + wsum[wid] + carry_s;
    if (idx < NN) { indptr[idx] = excl; fill[idx] = excl; }
    __syncthreads();
    if (tid == 0) carry_s += ctot;
    __syncthreads();
  }
  if (tid == 0) indptr[NN] = carry_s;
}

__global__ void fill_csr_k(const int* __restrict__ ei, int E, int NN,
                           int* __restrict__ fill, int* __restrict__ csr, int ET) {
  int e = blockIdx.x * blockDim.x + threadIdx.x;
  if (e >= E + NN) return;
  int s, d;
  if (e < E) { s = ei[e]; d = ei[E + e]; } else { s = e - E; d = e - E; }
  if ((unsigned)d >= (unsigned)NN) d = 0;
  if ((unsigned)s >= (unsigned)NN) s = 0;
  int slot = atomicAdd(&fill[d], 1);
  if ((unsigned)slot < (unsigned)ET) csr[slot] = s;
}

// ---------------- GAT aggregate + bias + GN + ELU (block per dst node) ----------------
__global__ __launch_bounds__(256) void gat_agg_gn_k(
    const __hip_bfloat16* __restrict__ h, const float* __restrict__ asrc,
    const float* __restrict__ adst, const int* __restrict__ indptr,
    const int* __restrict__ csr, const float* __restrict__ gbias,
    const float* __restrict__ gnw, const float* __restrict__ gnb,
    __hip_bfloat16* __restrict__ outp, int NN, int ET) {
  int n = blockIdx.x;
  int tid = threadIdx.x;
  int beg = indptr[n], end = indptr[n + 1];
  beg = max(0, min(beg, ET));
  end = max(beg, min(end, ET));
  int deg = end - beg;
  float adn = adst[n];
  __shared__ int sid[256];
  __shared__ float swt[256];
  __shared__ float red[4];

  float mx = -3.0e38f;                       // pass 1: max
  for (int j = tid; j < deg; j += 256) {
    int s = csr[beg + j];
    if ((unsigned)s >= (unsigned)NN) s = 0;
    float e = asrc[s] + adn;
    e = (e > 0.f) ? e : 0.2f * e;
    mx = fmaxf(mx, e);
  }
#pragma unroll
  for (int m = 32; m >= 1; m >>= 1) mx = fmaxf(mx, __shfl_xor(mx, m, 64));
  if ((tid & 63) == 0) red[tid >> 6] = mx;
  __syncthreads();
  mx = fmaxf(fmaxf(red[0], red[1]), fmaxf(red[2], red[3]));
  __syncthreads();

  float sm = 0.f;                            // pass 2: sum exp
  for (int j = tid; j < deg; j += 256) {
    int s = csr[beg + j];
    if ((unsigned)s >= (unsigned)NN) s = 0;
    float e = asrc[s] + adn;
    e = (e > 0.f) ? e : 0.2f * e;
    sm += __expf(fminf(e - mx, 0.f));
  }
#pragma unroll
  for (int m = 32; m >= 1; m >>= 1) sm += __shfl_xor(sm, m, 64);
  if ((tid & 63) == 0) red[tid >> 6] = sm;
  __syncthreads();
  sm = red[0] + red[1] + red[2] + red[3];
  float inv = 1.f / (sm + 1e-16f);

  float acc = 0.f;                           // pass 3: channel-parallel gather
  for (int cb = 0; cb < deg; cb += 256) {
    __syncthreads();
    int j = cb + tid;
    if (j < deg) {
      int s = csr[beg + j];
      if ((unsigned)s >= (unsigned)NN) s = 0;
      float e = asrc[s] + adn;
      e = (e > 0.f) ? e : 0.2f * e;
      sid[tid] = s;
      swt[tid] = __expf(fminf(e - mx, 0.f)) * inv;
    }
    __syncthreads();
    int cnt = min(256, deg - cb);
    for (int j2 = 0; j2 < cnt; ++j2)
      acc += swt[j2] * b2f(h[(size_t)sid[j2] * 256 + tid]);
  }

  float v = acc + gbias[tid];                // + bias, GN(8), ELU
  float s = v;
  s += __shfl_xor(s, 1, 64); s += __shfl_xor(s, 2, 64); s += __shfl_xor(s, 4, 64);
  float muv = s * 0.125f, d = v - muv;
  float q = d * d;
  q += __shfl_xor(q, 1, 64); q += __shfl_xor(q, 2, 64); q += __shfl_xor(q, 4, 64);
  float r = d * rsqrtf(q * 0.125f + 1e-5f) * gnw[tid] + gnb[tid];
  r = (r > 0.f) ? r : (__expf(r) - 1.f);
  outp[(size_t)n * 256 + tid] = f2b(r);
}

// ---------------- launch ----------------
extern "C" void kernel_launch(void* const* d_in, const int* in_sizes, int n_in,
                              void* d_out, int out_size, void* d_ws, size_t ws_size,
                              hipStream_t stream) {
  const float* x      = (const float*)d_in[0];
  const int*   ei     = (const int*)d_in[1];
  const float* pre_w  = (const float*)d_in[2];
  const float* pre_b  = (const float*)d_in[3];
  const float* lin1_w = (const float*)d_in[4];
  const float* lin1_b = (const float*)d_in[5];
  const float* n1_w   = (const float*)d_in[6];
  const float* n1_b   = (const float*)d_in[7];
  const float* g1_w   = (const float*)d_in[8];
  const float* g1_as  = (const float*)d_in[9];
  const float* g1_ad  = (const float*)d_in[10];
  const float* g1_b   = (const float*)d_in[11];
  const float* n2_w   = (const float*)d_in[12];
  const float* n2_b   = (const float*)d_in[13];
  const float* g2_w   = (const float*)d_in[14];
  const float* g2_as  = (const float*)d_in[15];
  const float* g2_ad  = (const float*)d_in[16];
  const float* g2_b   = (const float*)d_in[17];
  const float* n3_w   = (const float*)d_in[18];
  const float* n3_b   = (const float*)d_in[19];
  const float* lin2_w = (const float*)d_in[20];
  const float* lin2_b = (const float*)d_in[21];
  const float* skip_w = (const float*)d_in[22];
  const float* skip_b = (const float*)d_in[23];
  float* out = (float*)d_out;

  const int C_IN  = in_sizes[2];          // 256
  const int NN    = in_sizes[0] / C_IN;   // 40000
  const int E     = in_sizes[1] / 2;      // 640000
  const int ET    = E + NN;
  const int C_OUT = in_sizes[21];         // 512

  // bf16 scratch carved from d_out (fp32 NN*512 = 81.9MB; D0+D1 = 41MB, dead
  // before the final GEMM's full fp32 overwrite, which reads only Y(ws) and x).
  __hip_bfloat16* D0 = (__hip_bfloat16*)d_out;
  __hip_bfloat16* D1 = D0 + (size_t)NN * 256;

  // ws (~25 MB)
  char* basep = (char*)d_ws;
  size_t o = 0;
  auto alloc = [&](size_t bytes) { size_t r = o; o += (bytes + 255) & ~(size_t)255; return r; };
  __hip_bfloat16* Y      = (__hip_bfloat16*)(basep + alloc((size_t)NN * 256 * 2));
  __hip_bfloat16* Wcat   = (__hip_bfloat16*)(basep + alloc((size_t)458752 * 2));
  float*          asrc   = (float*)(basep + alloc((size_t)NN * 4));
  float*          adst   = (float*)(basep + alloc((size_t)NN * 4));
  int*            indptr = (int*)(basep + alloc((size_t)(NN + 1) * 4));
  int*            counts = (int*)(basep + alloc((size_t)NN * 4));
  int*            fill   = (int*)(basep + alloc((size_t)NN * 4));
  int*            csr    = (int*)(basep + alloc((size_t)ET * 4));
  __hip_bfloat16* Wlin1 = Wcat;
  __hip_bfloat16* Wg1   = Wcat + 65536;
  __hip_bfloat16* Wg2   = Wcat + 131072;
  __hip_bfloat16* Wlin2 = Wcat + 196608;
  __hip_bfloat16* Wskip = Wcat + 327680;

  dim3 blk(256);
  conv_w_k<<<(458752 / 4 + 255) / 256, blk, 0, stream>>>(lin1_w, g1_w, g2_w, lin2_w, skip_w, Wcat);
  zero_k<<<(NN + 255) / 256, blk, 0, stream>>>(counts, NN);
  count_deg_k<<<(ET + 255) / 256, blk, 0, stream>>>(ei, E, NN, counts);
  scan_k<<<1, 1024, 0, stream>>>(counts, indptr, fill, NN);
  fill_csr_k<<<(ET + 255) / 256, blk, 0, stream>>>(ei, E, NN, fill, csr, ET);

  gn_elu_k<<<(NN * 32 + 255) / 256, blk, 0, stream>>>(x, pre_w, pre_b, D0, NN * 32);
  gemm_f<0><<<dim3(1, NN / 16), blk, 0, stream>>>(D0, nullptr, Wlin1, nullptr, lin1_b, nullptr,
                                                  n1_w, n1_b, nullptr, nullptr, Y, nullptr, nullptr, nullptr, 256);
  gemm_f<1><<<dim3(1, NN / 16), blk, 0, stream>>>(Y, nullptr, Wg1, nullptr, nullptr, nullptr,
                                                  nullptr, nullptr, g1_as, g1_ad, D0, nullptr, asrc, adst, 256);
  gat_agg_gn_k<<<NN, blk, 0, stream>>>(D0, asrc, adst, indptr, csr, g1_b, n2_w, n2_b, D1, NN, ET);
  gemm_f<1><<<dim3(1, NN / 16), blk, 0, stream>>>(D1, nullptr, Wg2, nullptr, nullptr, nullptr,
                                                  nullptr, nullptr, g2_as, g2_ad, D0, nullptr, asrc, adst, 256);
  gat_agg_gn_k<<<NN, blk, 0, stream>>>(D0, asrc, adst, indptr, csr, g2_b, n3_w, n3_b, Y, NN, ET);
  gemm_f<2><<<dim3(C_OUT / 256, NN / 16), blk, 0, stream>>>(Y, x, Wlin2, Wskip, lin2_b, skip_b,
                                                            nullptr, nullptr, nullptr, nullptr, nullptr, out, nullptr, nullptr, C_OUT);
}

// Round 4
// 520.126 us; speedup vs baseline: 1.6024x; 1.6024x over previous
//
#include <hip/hip_runtime.h>
#include <hip/hip_bf16.h>

// GraphResBlock on MI355X — round 4: LDS-tiled MFMA GEMMs (128x128xBK32, m93-style
// register-prefetch staging) + single-pass wave-per-node GAT aggregation.
// All fp32 in / fp32 out; bf16 MFMA internally.
//
// Dataflow (D0/D1 = bf16 scratch carved from d_out's 82MB; Y = bf16 in ws;
// all activation buffers padded to NP=40064 rows so only the final store guards):
//   conv_w:    5 fp32 weights -> bf16 Wcat (ws)
//   gn_elu:    x(f32) -> D0                    (GN(pre)+ELU)
//   gemm<0>:   D0 -> Y                         (lin1 + GN1 + ELU)
//   gemm<1>:   Y  -> D0 (h1) + asrc/adst       (g1 lin; alpha dots via atomics)
//   agg:       D0 -> D1                        (online-softmax agg + g1_b + GN2 + ELU)
//   gemm<1>:   D1 -> D0 (h2) + asrc/adst
//   agg:       D0 -> Y                         (+ g2_b + GN3 + ELU)
//   gemm<2>:   (Y bf16 | x f32-streamed) -> d_out f32   (lin2 + skip, K=512)

typedef __bf16 bf16x8 __attribute__((ext_vector_type(8)));
typedef float floatx4 __attribute__((ext_vector_type(4)));

__device__ __forceinline__ __hip_bfloat16 f2b(float f) { return __float2bfloat16(f); }
__device__ __forceinline__ float b2f(__hip_bfloat16 v) { return __bfloat162float(v); }
__device__ __forceinline__ float bits2f(unsigned short u) {
  return __uint_as_float((unsigned)u << 16);
}

__device__ __forceinline__ bf16x8 cvt8(const float* p) {
  float4 a = *(const float4*)p, b = *(const float4*)(p + 4);
  bf16x8 r;
  r[0] = (__bf16)a.x; r[1] = (__bf16)a.y; r[2] = (__bf16)a.z; r[3] = (__bf16)a.w;
  r[4] = (__bf16)b.x; r[5] = (__bf16)b.y; r[6] = (__bf16)b.z; r[7] = (__bf16)b.w;
  return r;
}

// ---------------- weight fp32 -> bf16 pack ----------------
__global__ void conv_w_k(const float* __restrict__ s0, const float* __restrict__ s1,
                         const float* __restrict__ s2, const float* __restrict__ s3,
                         const float* __restrict__ s4, __hip_bfloat16* __restrict__ d) {
  int i = (blockIdx.x * blockDim.x + threadIdx.x) * 4;
  if (i >= 458752) return;
  const float* s; int off;
  if      (i < 65536)  { s = s0; off = 0; }
  else if (i < 131072) { s = s1; off = 65536; }
  else if (i < 196608) { s = s2; off = 131072; }
  else if (i < 327680) { s = s3; off = 196608; }
  else                 { s = s4; off = 327680; }
  float4 v = *(const float4*)(s + (i - off));
  union { ushort4 u; __hip_bfloat16 h[4]; } st;
  st.h[0] = f2b(v.x); st.h[1] = f2b(v.y); st.h[2] = f2b(v.z); st.h[3] = f2b(v.w);
  *(ushort4*)(d + i) = st.u;
}

// ---------------- pre GroupNorm(8) + ELU: fp32 -> bf16 ----------------
__global__ void gn_elu_k(const float* __restrict__ x, const float* __restrict__ w,
                         const float* __restrict__ b, __hip_bfloat16* __restrict__ o, int ng) {
  int g = blockIdx.x * blockDim.x + threadIdx.x;
  if (g >= ng) return;
  int gi = g & 31;
  size_t basei = (size_t)g * 8;
  float4 u0 = *(const float4*)(x + basei), u1 = *(const float4*)(x + basei + 4);
  float f[8] = {u0.x, u0.y, u0.z, u0.w, u1.x, u1.y, u1.z, u1.w};
  float mu = 0.f;
#pragma unroll
  for (int i = 0; i < 8; i++) mu += f[i];
  mu *= 0.125f;
  float var = 0.f;
#pragma unroll
  for (int i = 0; i < 8; i++) { float d = f[i] - mu; var += d * d; }
  float inv = rsqrtf(var * 0.125f + 1e-5f);
  union { uint4 u; __hip_bfloat16 h[8]; } st;
#pragma unroll
  for (int i = 0; i < 8; i++) {
    float vv = (f[i] - mu) * inv * w[gi * 8 + i] + b[gi * 8 + i];
    vv = (vv > 0.f) ? vv : (__expf(vv) - 1.f);
    st.h[i] = f2b(vv);
  }
  *(uint4*)(o + basei) = st.u;
}

// ---------------- LDS-tiled MFMA GEMM: 128x128 tile, BK=32, 256 threads ----------------
// MODE 0: outB = ELU(GN8(A@W^T + bias)) bf16 (Nc=256)
// MODE 1: outB = A@W^T bf16; atomicAdd row-dots with avs/avd into asrc/adst
// MODE 2: outF = Abf@W^T + Af32@W2^T + bias + bias2 (fp32, Nc=512), rows < Mreal
template <int MODE>
__global__ __launch_bounds__(256) void gemm_t(
    const __hip_bfloat16* __restrict__ A, const float* __restrict__ Af32,
    const __hip_bfloat16* __restrict__ W, const __hip_bfloat16* __restrict__ W2,
    const float* __restrict__ bias, const float* __restrict__ bias2,
    const float* __restrict__ gnw, const float* __restrict__ gnb,
    const float* __restrict__ avs, const float* __restrict__ avd,
    __hip_bfloat16* __restrict__ outB, float* __restrict__ outF,
    float* __restrict__ asrc, float* __restrict__ adst, int Nc, int Mreal) {
  const int tid = threadIdx.x;
  const int wv = tid >> 6, lane = tid & 63;
  const int l16 = lane & 15, quad = lane >> 4;
  const int wm = wv >> 1, wn = wv & 1;                 // 2x2 wave grid, 64x64 each
  const int rows0 = blockIdx.y * 128, col0 = blockIdx.x * 128;
  const int srow = tid >> 2;                           // staging row 0..63
  const int skc = (tid & 3) * 8;                       // staging k-chunk offset
  __shared__ __align__(16) __hip_bfloat16 sA[128 * 32];
  __shared__ __align__(16) __hip_bfloat16 sB[128 * 32];
  const int lo0 = srow * 32 + skc, lo1 = (srow + 64) * 32 + skc;

  floatx4 acc[4][4];
#pragma unroll
  for (int a = 0; a < 4; ++a)
#pragma unroll
    for (int b = 0; b < 4; ++b) acc[a][b] = (floatx4){0.f, 0.f, 0.f, 0.f};

  // prefetch k-tile 0
  uint4 pa0, pa1, pb0, pb1;
  pa0 = *(const uint4*)(A + (size_t)(rows0 + srow) * 256 + skc);
  pa1 = *(const uint4*)(A + (size_t)(rows0 + srow + 64) * 256 + skc);
  pb0 = *(const uint4*)(W + (size_t)(col0 + srow) * 256 + skc);
  pb1 = *(const uint4*)(W + (size_t)(col0 + srow + 64) * 256 + skc);

  const int NK = (MODE == 2) ? 16 : 8;
#pragma unroll
  for (int kt = 0; kt < NK; ++kt) {
    const bool sec = (MODE == 2) && (kt >= 8);
    __syncthreads();
    if (!sec) { *(uint4*)(sA + lo0) = pa0; *(uint4*)(sA + lo1) = pa1; }
    *(uint4*)(sB + lo0) = pb0; *(uint4*)(sB + lo1) = pb1;
    __syncthreads();
    // prefetch next k-tile (overlaps with compute below)
    const int ktn = kt + 1;
    if (ktn < NK) {
      const bool secn = (MODE == 2) && (ktn >= 8);
      const int kkn = secn ? (ktn - 8) * 32 : ktn * 32;
      const __hip_bfloat16* Wn = secn ? W2 : W;
      if (!secn) {
        pa0 = *(const uint4*)(A + (size_t)(rows0 + srow) * 256 + kkn + skc);
        pa1 = *(const uint4*)(A + (size_t)(rows0 + srow + 64) * 256 + kkn + skc);
      }
      pb0 = *(const uint4*)(Wn + (size_t)(col0 + srow) * 256 + kkn + skc);
      pb1 = *(const uint4*)(Wn + (size_t)(col0 + srow + 64) * 256 + kkn + skc);
    }
    bf16x8 af[4], bfr[4];
    if (sec) {                                        // stream fp32 x -> bf16 frags
      const int kk = (kt - 8) * 32;
#pragma unroll
      for (int ri = 0; ri < 4; ++ri) {
        int row = rows0 + wm * 64 + ri * 16 + l16;
        row = min(row, Mreal - 1);
        af[ri] = cvt8(Af32 + (size_t)row * 256 + kk + quad * 8);
      }
    } else {
#pragma unroll
      for (int ri = 0; ri < 4; ++ri)
        af[ri] = *(const bf16x8*)(sA + (wm * 64 + ri * 16 + l16) * 32 + quad * 8);
    }
#pragma unroll
    for (int ci = 0; ci < 4; ++ci)
      bfr[ci] = *(const bf16x8*)(sB + (wn * 64 + ci * 16 + l16) * 32 + quad * 8);
#pragma unroll
    for (int ri = 0; ri < 4; ++ri)
#pragma unroll
      for (int ci = 0; ci < 4; ++ci)
        acc[ri][ci] = __builtin_amdgcn_mfma_f32_16x16x32_bf16(af[ri], bfr[ci], acc[ri][ci], 0, 0, 0);
  }

  // epilogues; C/D layout: col = l16 (+ci*16), row = quad*4 + i (+ri*16)
  if (MODE == 0) {
#pragma unroll
    for (int ri = 0; ri < 4; ++ri)
#pragma unroll
      for (int ci = 0; ci < 4; ++ci) {
        int col = col0 + wn * 64 + ci * 16 + l16;
        float bs = bias[col], gw = gnw[col], gb = gnb[col];
#pragma unroll
        for (int i = 0; i < 4; ++i) {
          float v = acc[ri][ci][i] + bs;
          float s = v;                                 // GN over 8 cols: lane bits 0..2
          s += __shfl_xor(s, 1, 64); s += __shfl_xor(s, 2, 64); s += __shfl_xor(s, 4, 64);
          float mu = s * 0.125f, d = v - mu;
          float q = d * d;
          q += __shfl_xor(q, 1, 64); q += __shfl_xor(q, 2, 64); q += __shfl_xor(q, 4, 64);
          float r = d * rsqrtf(q * 0.125f + 1e-5f) * gw + gb;
          r = (r > 0.f) ? r : (__expf(r) - 1.f);
          outB[(size_t)(rows0 + wm * 64 + ri * 16 + quad * 4 + i) * 256 + col] = f2b(r);
        }
      }
  } else if (MODE == 1) {
#pragma unroll
    for (int ri = 0; ri < 4; ++ri) {
      float ps[4] = {0.f, 0.f, 0.f, 0.f}, pd[4] = {0.f, 0.f, 0.f, 0.f};
#pragma unroll
      for (int ci = 0; ci < 4; ++ci) {
        int col = col0 + wn * 64 + ci * 16 + l16;
        float wsv = avs[col], wdv = avd[col];
#pragma unroll
        for (int i = 0; i < 4; ++i) {
          float v = acc[ri][ci][i];
          outB[(size_t)(rows0 + wm * 64 + ri * 16 + quad * 4 + i) * 256 + col] = f2b(v);
          ps[i] += v * wsv; pd[i] += v * wdv;
        }
      }
#pragma unroll
      for (int i = 0; i < 4; ++i) {
        ps[i] += __shfl_xor(ps[i], 1, 64); ps[i] += __shfl_xor(ps[i], 2, 64);
        ps[i] += __shfl_xor(ps[i], 4, 64); ps[i] += __shfl_xor(ps[i], 8, 64);
        pd[i] += __shfl_xor(pd[i], 1, 64); pd[i] += __shfl_xor(pd[i], 2, 64);
        pd[i] += __shfl_xor(pd[i], 4, 64); pd[i] += __shfl_xor(pd[i], 8, 64);
        if (l16 == 0) {
          int row = rows0 + wm * 64 + ri * 16 + quad * 4 + i;
          atomicAdd(&asrc[row], ps[i]);
          atomicAdd(&adst[row], pd[i]);
        }
      }
    }
  } else {
#pragma unroll
    for (int ri = 0; ri < 4; ++ri)
#pragma unroll
      for (int ci = 0; ci < 4; ++ci) {
        int col = col0 + wn * 64 + ci * 16 + l16;
        float bs = bias[col] + bias2[col];
#pragma unroll
        for (int i = 0; i < 4; ++i) {
          int row = rows0 + wm * 64 + ri * 16 + quad * 4 + i;
          if (row < Mreal) outF[(size_t)row * Nc + col] = acc[ri][ci][i] + bs;
        }
      }
  }
}

// ---------------- CSR build (by dst), clamped ----------------
__global__ void zero_k(int* p, int n) {
  int i = blockIdx.x * blockDim.x + threadIdx.x;
  if (i < n) p[i] = 0;
}
__global__ void zero_f_k(float* p, int n) {
  int i = blockIdx.x * blockDim.x + threadIdx.x;
  if (i < n) p[i] = 0.f;
}

__global__ void count_deg_k(const int* __restrict__ ei, int E, int NN, int* __restrict__ counts) {
  int e = blockIdx.x * blockDim.x + threadIdx.x;
  if (e >= E + NN) return;
  int d = (e < E) ? ei[E + e] : (e - E);
  if ((unsigned)d >= (unsigned)NN) d = 0;
  atomicAdd(&counts[d], 1);
}

__global__ void scan_k(const int* __restrict__ counts, int* __restrict__ indptr,
                       int* __restrict__ fill, int NN) {
  __shared__ int wsum[16];
  __shared__ int carry_s;
  __shared__ int ctot;
  int tid = threadIdx.x;
  int lane = tid & 63, wid = tid >> 6;
  if (tid == 0) carry_s = 0;
  __syncthreads();
  for (int base = 0; base < NN; base += 1024) {
    int idx = base + tid;
    int v = (idx < NN) ? counts[idx] : 0;
    int s = v;
#pragma unroll
    for (int off = 1; off < 64; off <<= 1) {
      int t = __shfl_up(s, off, 64);
      if (lane >= off) s += t;
    }
    if (lane == 63) wsum[wid] = s;
    __syncthreads();
    if (tid == 0) {
      int run = 0;
#pragma unroll
      for (int i = 0; i < 16; i++) { int t = wsum[i]; wsum[i] = run; run += t; }
      ctot = run;
    }
    __syncthreads();
    int excl = s - v + wsum[wid] + carry_s;
    if (idx < NN) { indptr[idx] = excl; fill[idx] = excl; }
    __syncthreads();
    if (tid == 0) carry_s += ctot;
    __syncthreads();
  }
  if (tid == 0) indptr[NN] = carry_s;
}

__global__ void fill_csr_k(const int* __restrict__ ei, int E, int NN,
                           int* __restrict__ fill, int* __restrict__ csr, int ET) {
  int e = blockIdx.x * blockDim.x + threadIdx.x;
  if (e >= E + NN) return;
  int s, d;
  if (e < E) { s = ei[e]; d = ei[E + e]; } else { s = e - E; d = e - E; }
  if ((unsigned)d >= (unsigned)NN) d = 0;
  if ((unsigned)s >= (unsigned)NN) s = 0;
  int slot = atomicAdd(&fill[d], 1);
  if ((unsigned)slot < (unsigned)ET) csr[slot] = s;
}

// ---------------- GAT aggregate: wave per dst node, single-pass online softmax ----------------
// lane covers channels lane*4..lane*4+3 (ushort4 = 8B/lane gathers, no LDS, no syncs).
__global__ __launch_bounds__(256) void gat_agg_gn_k(
    const __hip_bfloat16* __restrict__ h, const float* __restrict__ asrc,
    const float* __restrict__ adst, const int* __restrict__ indptr,
    const int* __restrict__ csr, const float* __restrict__ gbias,
    const float* __restrict__ gnw, const float* __restrict__ gnb,
    __hip_bfloat16* __restrict__ outp, int NN, int ET) {
  int n = blockIdx.x * 4 + (threadIdx.x >> 6);
  int lane = threadIdx.x & 63;
  if (n >= NN) return;
  int beg = indptr[n], end = indptr[n + 1];
  beg = max(0, min(beg, ET));
  end = max(beg, min(end, ET));
  int deg = end - beg;
  float adn = adst[n];

  float m_run = -3.0e38f, l_run = 0.f;
  float a0 = 0.f, a1 = 0.f, a2 = 0.f, a3 = 0.f;

  for (int cb = 0; cb < deg; cb += 64) {
    int j = cb + lane;
    int sid = 0;
    float e = -3.0e38f;
    if (j < deg) {
      sid = csr[beg + j];
      if ((unsigned)sid >= (unsigned)NN) sid = 0;
      e = asrc[sid] + adn;
      e = (e > 0.f) ? e : 0.2f * e;                  // leaky_relu 0.2
    }
    float cm = e;
#pragma unroll
    for (int m = 32; m >= 1; m >>= 1) cm = fmaxf(cm, __shfl_xor(cm, m, 64));
    float mnew = fmaxf(m_run, cm);
    float scale = __expf(m_run - mnew);              // <=1; first chunk: exp(-huge)=0
    l_run *= scale; a0 *= scale; a1 *= scale; a2 *= scale; a3 *= scale;
    float w = (j < deg) ? __expf(e - mnew) : 0.f;    // arg <= 0
    float ws = w;
#pragma unroll
    for (int m = 32; m >= 1; m >>= 1) ws += __shfl_xor(ws, m, 64);
    l_run += ws;
    int cnt = min(64, deg - cb);
    for (int t = 0; t < cnt; ++t) {
      int s = __shfl(sid, t, 64);
      float wt = __shfl(w, t, 64);
      ushort4 u = *((const ushort4*)(h + (size_t)s * 256) + lane);
      a0 += wt * bits2f(u.x);
      a1 += wt * bits2f(u.y);
      a2 += wt * bits2f(u.z);
      a3 += wt * bits2f(u.w);
    }
    m_run = mnew;
  }
  float inv = 1.f / (l_run + 1e-16f);
  int c0 = lane * 4;
  float v0 = a0 * inv + gbias[c0 + 0];
  float v1 = a1 * inv + gbias[c0 + 1];
  float v2 = a2 * inv + gbias[c0 + 2];
  float v3 = a3 * inv + gbias[c0 + 3];
  // GroupNorm(8): group = 2 adjacent lanes
  float s = v0 + v1 + v2 + v3;
  s += __shfl_xor(s, 1, 64);
  float mu = s * 0.125f;
  float d0 = v0 - mu, d1 = v1 - mu, d2 = v2 - mu, d3 = v3 - mu;
  float q = d0 * d0 + d1 * d1 + d2 * d2 + d3 * d3;
  q += __shfl_xor(q, 1, 64);
  float rs = rsqrtf(q * 0.125f + 1e-5f);
  float r0 = d0 * rs * gnw[c0 + 0] + gnb[c0 + 0];
  float r1 = d1 * rs * gnw[c0 + 1] + gnb[c0 + 1];
  float r2 = d2 * rs * gnw[c0 + 2] + gnb[c0 + 2];
  float r3 = d3 * rs * gnw[c0 + 3] + gnb[c0 + 3];
  r0 = (r0 > 0.f) ? r0 : (__expf(r0) - 1.f);
  r1 = (r1 > 0.f) ? r1 : (__expf(r1) - 1.f);
  r2 = (r2 > 0.f) ? r2 : (__expf(r2) - 1.f);
  r3 = (r3 > 0.f) ? r3 : (__expf(r3) - 1.f);
  union { ushort4 u; __hip_bfloat16 b[4]; } st;
  st.b[0] = f2b(r0); st.b[1] = f2b(r1); st.b[2] = f2b(r2); st.b[3] = f2b(r3);
  *((ushort4*)(outp + (size_t)n * 256) + lane) = st.u;
}

// ---------------- launch ----------------
extern "C" void kernel_launch(void* const* d_in, const int* in_sizes, int n_in,
                              void* d_out, int out_size, void* d_ws, size_t ws_size,
                              hipStream_t stream) {
  const float* x      = (const float*)d_in[0];
  const int*   ei     = (const int*)d_in[1];
  const float* pre_w  = (const float*)d_in[2];
  const float* pre_b  = (const float*)d_in[3];
  const float* lin1_w = (const float*)d_in[4];
  const float* lin1_b = (const float*)d_in[5];
  const float* n1_w   = (const float*)d_in[6];
  const float* n1_b   = (const float*)d_in[7];
  const float* g1_w   = (const float*)d_in[8];
  const float* g1_as  = (const float*)d_in[9];
  const float* g1_ad  = (const float*)d_in[10];
  const float* g1_b   = (const float*)d_in[11];
  const float* n2_w   = (const float*)d_in[12];
  const float* n2_b   = (const float*)d_in[13];
  const float* g2_w   = (const float*)d_in[14];
  const float* g2_as  = (const float*)d_in[15];
  const float* g2_ad  = (const float*)d_in[16];
  const float* g2_b   = (const float*)d_in[17];
  const float* n3_w   = (const float*)d_in[18];
  const float* n3_b   = (const float*)d_in[19];
  const float* lin2_w = (const float*)d_in[20];
  const float* lin2_b = (const float*)d_in[21];
  const float* skip_w = (const float*)d_in[22];
  const float* skip_b = (const float*)d_in[23];
  float* out = (float*)d_out;

  const int C_IN  = in_sizes[2];          // 256
  const int NN    = in_sizes[0] / C_IN;   // 40000
  const int E     = in_sizes[1] / 2;      // 640000
  const int ET    = E + NN;
  const int C_OUT = in_sizes[21];         // 512
  const int NP    = (NN + 127) & ~127;    // 40064, M padded to tile

  // bf16 scratch carved from d_out (2 x NP*256*2B = 41MB << 82MB out; dead before
  // the final GEMM, which reads only Y(ws) + x(input) and overwrites all of out).
  __hip_bfloat16* D0 = (__hip_bfloat16*)d_out;
  __hip_bfloat16* D1 = D0 + (size_t)NP * 256;

  // ws (~24.5 MB)
  char* basep = (char*)d_ws;
  size_t o = 0;
  auto alloc = [&](size_t bytes) { size_t r = o; o += (bytes + 255) & ~(size_t)255; return r; };
  __hip_bfloat16* Y      = (__hip_bfloat16*)(basep + alloc((size_t)NP * 256 * 2));
  __hip_bfloat16* Wcat   = (__hip_bfloat16*)(basep + alloc((size_t)458752 * 2));
  float*          asrc   = (float*)(basep + alloc((size_t)NP * 4));
  float*          adst   = (float*)(basep + alloc((size_t)NP * 4));
  int*            indptr = (int*)(basep + alloc((size_t)(NN + 1) * 4));
  int*            counts = (int*)(basep + alloc((size_t)NN * 4));
  int*            fill   = (int*)(basep + alloc((size_t)NN * 4));
  int*            csr    = (int*)(basep + alloc((size_t)ET * 4));
  __hip_bfloat16* Wlin1 = Wcat;
  __hip_bfloat16* Wg1   = Wcat + 65536;
  __hip_bfloat16* Wg2   = Wcat + 131072;
  __hip_bfloat16* Wlin2 = Wcat + 196608;
  __hip_bfloat16* Wskip = Wcat + 327680;

  dim3 blk(256);
  conv_w_k<<<(458752 / 4 + 255) / 256, blk, 0, stream>>>(lin1_w, g1_w, g2_w, lin2_w, skip_w, Wcat);
  zero_k<<<(NN + 255) / 256, blk, 0, stream>>>(counts, NN);
  zero_f_k<<<(2 * NP + 255) / 256, blk, 0, stream>>>(asrc, 2 * NP);  // asrc+adst contiguous
  count_deg_k<<<(ET + 255) / 256, blk, 0, stream>>>(ei, E, NN, counts);
  scan_k<<<1, 1024, 0, stream>>>(counts, indptr, fill, NN);
  fill_csr_k<<<(ET + 255) / 256, blk, 0, stream>>>(ei, E, NN, fill, csr, ET);

  gn_elu_k<<<(NN * 32 + 255) / 256, blk, 0, stream>>>(x, pre_w, pre_b, D0, NN * 32);
  // lin1 + GN1 + ELU
  gemm_t<0><<<dim3(2, NP / 128), blk, 0, stream>>>(D0, nullptr, Wlin1, nullptr, lin1_b, nullptr,
                                                   n1_w, n1_b, nullptr, nullptr, Y, nullptr,
                                                   nullptr, nullptr, 256, NN);
  // GAT1
  gemm_t<1><<<dim3(2, NP / 128), blk, 0, stream>>>(Y, nullptr, Wg1, nullptr, nullptr, nullptr,
                                                   nullptr, nullptr, g1_as, g1_ad, D0, nullptr,
                                                   asrc, adst, 256, NN);
  gat_agg_gn_k<<<NN / 4, blk, 0, stream>>>(D0, asrc, adst, indptr, csr, g1_b, n2_w, n2_b, D1, NN, ET);
  // GAT2
  zero_f_k<<<(2 * NP + 255) / 256, blk, 0, stream>>>(asrc, 2 * NP);
  gemm_t<1><<<dim3(2, NP / 128), blk, 0, stream>>>(D1, nullptr, Wg2, nullptr, nullptr, nullptr,
                                                   nullptr, nullptr, g2_as, g2_ad, D0, nullptr,
                                                   asrc, adst, 256, NN);
  gat_agg_gn_k<<<NN / 4, blk, 0, stream>>>(D0, asrc, adst, indptr, csr, g2_b, n3_w, n3_b, Y, NN, ET);
  // lin2 + skip fused -> out (K=512)
  gemm_t<2><<<dim3(C_OUT / 128, NP / 128), blk, 0, stream>>>(Y, x, Wlin2, Wskip, lin2_b, skip_b,
                                                             nullptr, nullptr, nullptr, nullptr,
                                                             nullptr, out, nullptr, nullptr, C_OUT, NN);
}

// Round 5
// 438.817 us; speedup vs baseline: 1.8993x; 1.1853x over previous
//
#include <hip/hip_runtime.h>
#include <hip/hip_bf16.h>

// GraphResBlock on MI355X — round 5.
// GEMMs: 64row x 256col tiles, BK=32, dbuf LDS, 4 waves (each 64x64), MFMA bf16.
// Final GEMM reads pre-converted bf16 xb (MODE 2) if ws_size permits, else streams fp32 (MODE 3).
// Alpha dots: block owns full rows -> plain stores (no atomics/zeroing).
// GAT agg: wave/node, no-max softmax (clamped, shift-invariant), 16B/lane 2-edge gather.
// CSR: parallel 3-stage scan.

typedef __bf16 bf16x8 __attribute__((ext_vector_type(8)));
typedef float floatx4 __attribute__((ext_vector_type(4)));

__device__ __forceinline__ __hip_bfloat16 f2b(float f) { return __float2bfloat16(f); }
__device__ __forceinline__ float bits2f(unsigned u) { return __uint_as_float(u << 16); }

__device__ __forceinline__ bf16x8 cvt8(const float* p) {
  float4 a = *(const float4*)p, b = *(const float4*)(p + 4);
  bf16x8 r;
  r[0] = (__bf16)a.x; r[1] = (__bf16)a.y; r[2] = (__bf16)a.z; r[3] = (__bf16)a.w;
  r[4] = (__bf16)b.x; r[5] = (__bf16)b.y; r[6] = (__bf16)b.z; r[7] = (__bf16)b.w;
  return r;
}

// ---------------- weight fp32 -> bf16 pack ----------------
__global__ __launch_bounds__(256) void conv_w_k(
    const float* __restrict__ s0, const float* __restrict__ s1,
    const float* __restrict__ s2, const float* __restrict__ s3,
    const float* __restrict__ s4, __hip_bfloat16* __restrict__ d) {
  int i = (blockIdx.x * 256 + threadIdx.x) * 4;
  if (i >= 458752) return;
  const float* s; int off;
  if      (i < 65536)  { s = s0; off = 0; }
  else if (i < 131072) { s = s1; off = 65536; }
  else if (i < 196608) { s = s2; off = 131072; }
  else if (i < 327680) { s = s3; off = 196608; }
  else                 { s = s4; off = 327680; }
  float4 v = *(const float4*)(s + (i - off));
  union { ushort4 u; __hip_bfloat16 h[4]; } st;
  st.h[0] = f2b(v.x); st.h[1] = f2b(v.y); st.h[2] = f2b(v.z); st.h[3] = f2b(v.w);
  *(ushort4*)(d + i) = st.u;
}

// ---------------- pre GroupNorm(8) + ELU (+ optional raw x -> bf16) ----------------
__global__ __launch_bounds__(256) void gn_elu_k(
    const float* __restrict__ x, const float* __restrict__ w, const float* __restrict__ b,
    __hip_bfloat16* __restrict__ o, __hip_bfloat16* __restrict__ xb, int ng) {
  int g = blockIdx.x * 256 + threadIdx.x;
  if (g >= ng) return;
  int gi = g & 31;
  size_t basei = (size_t)g * 8;
  float4 u0 = *(const float4*)(x + basei), u1 = *(const float4*)(x + basei + 4);
  float f[8] = {u0.x, u0.y, u0.z, u0.w, u1.x, u1.y, u1.z, u1.w};
  if (xb) {
    union { uint4 u; __hip_bfloat16 h[8]; } xs;
#pragma unroll
    for (int i = 0; i < 8; i++) xs.h[i] = f2b(f[i]);
    *(uint4*)(xb + basei) = xs.u;
  }
  float mu = 0.f;
#pragma unroll
  for (int i = 0; i < 8; i++) mu += f[i];
  mu *= 0.125f;
  float var = 0.f;
#pragma unroll
  for (int i = 0; i < 8; i++) { float d = f[i] - mu; var += d * d; }
  float inv = rsqrtf(var * 0.125f + 1e-5f);
  union { uint4 u; __hip_bfloat16 h[8]; } st;
#pragma unroll
  for (int i = 0; i < 8; i++) {
    float vv = (f[i] - mu) * inv * w[gi * 8 + i] + b[gi * 8 + i];
    vv = (vv > 0.f) ? vv : (__expf(vv) - 1.f);
    st.h[i] = f2b(vv);
  }
  *(uint4*)(o + basei) = st.u;
}

// ---------------- MFMA GEMM: 64 x 256 tile, BK=32, dbuf LDS, 256 threads ----------------
// MODE 0: outB = ELU(GN8(A@W^T + bias)) bf16, Nc=256
// MODE 1: outB = A@W^T bf16; asrc/adst = row dots (plain stores), Nc=256
// MODE 2: outF = A@W^T + A2@W2^T + bias + bias2 fp32, Nc=512 (A2 bf16 staged)
// MODE 3: like 2 but second half streams Af32 (fp32 x) per-wave
template <int MODE>
__global__ __launch_bounds__(256, 3) void gemm_t(
    const __hip_bfloat16* __restrict__ A, const __hip_bfloat16* __restrict__ A2,
    const float* __restrict__ Af32,
    const __hip_bfloat16* __restrict__ W, const __hip_bfloat16* __restrict__ W2,
    const float* __restrict__ bias, const float* __restrict__ bias2,
    const float* __restrict__ gnw, const float* __restrict__ gnb,
    const float* __restrict__ avs, const float* __restrict__ avd,
    __hip_bfloat16* __restrict__ outB, float* __restrict__ outF,
    float* __restrict__ asrc, float* __restrict__ adst, int Nc, int Mreal) {
  const int tid = threadIdx.x;
  const int wn = tid >> 6, lane = tid & 63;
  const int l16 = lane & 15, quad = lane >> 4;
  const int rows0 = blockIdx.y * 64;
  const int col0 = blockIdx.x * 256;
  const int srow = tid >> 2, skc = (tid & 3) * 8;
  __shared__ __align__(16) __hip_bfloat16 sA[2][64 * 32];
  __shared__ __align__(16) __hip_bfloat16 sB[2][256 * 32];
  __shared__ float sRed[2][64][4];
  const int loA = tid * 8;  // = srow*32 + skc

  floatx4 acc[4][4];
#pragma unroll
  for (int a = 0; a < 4; ++a)
#pragma unroll
    for (int b = 0; b < 4; ++b) acc[a][b] = (floatx4){0.f, 0.f, 0.f, 0.f};

  const int NK = (MODE >= 2) ? 16 : 8;
  uint4 pa, pb[4];
  pa = *(const uint4*)(A + (size_t)(rows0 + srow) * 256 + skc);
#pragma unroll
  for (int h = 0; h < 4; ++h)
    pb[h] = *(const uint4*)(W + (size_t)(col0 + srow + h * 64) * 256 + skc);
  *(uint4*)(&sA[0][loA]) = pa;
#pragma unroll
  for (int h = 0; h < 4; ++h) *(uint4*)(&sB[0][loA + h * 2048]) = pb[h];
  __syncthreads();

#pragma unroll
  for (int kt = 0; kt < NK; ++kt) {
    const int cur = kt & 1, nxt = cur ^ 1;
    const int ktn = kt + 1;
    const bool nsec = (MODE >= 2) && (ktn >= 8);
    const bool nstageA = (ktn < NK) && !(MODE == 3 && nsec);
    if (ktn < NK) {
      const int kkn = (ktn & 7) * 32;
      const __hip_bfloat16* Wb = nsec ? W2 : W;
      if (nstageA) {
        const __hip_bfloat16* Ab = (MODE == 2 && nsec) ? A2 : A;
        pa = *(const uint4*)(Ab + (size_t)(rows0 + srow) * 256 + kkn + skc);
      }
#pragma unroll
      for (int h = 0; h < 4; ++h)
        pb[h] = *(const uint4*)(Wb + (size_t)(col0 + srow + h * 64) * 256 + kkn + skc);
    }
    bf16x8 af[4], bfr[4];
    if (MODE == 3 && kt >= 8) {
      const int kk = (kt & 7) * 32;
#pragma unroll
      for (int ri = 0; ri < 4; ++ri) {
        int row = min(rows0 + ri * 16 + l16, Mreal - 1);
        af[ri] = cvt8(Af32 + (size_t)row * 256 + kk + quad * 8);
      }
    } else {
#pragma unroll
      for (int ri = 0; ri < 4; ++ri)
        af[ri] = *(const bf16x8*)(&sA[cur][(ri * 16 + l16) * 32 + quad * 8]);
    }
#pragma unroll
    for (int ci = 0; ci < 4; ++ci)
      bfr[ci] = *(const bf16x8*)(&sB[cur][(wn * 64 + ci * 16 + l16) * 32 + quad * 8]);
#pragma unroll
    for (int ri = 0; ri < 4; ++ri)
#pragma unroll
      for (int ci = 0; ci < 4; ++ci)
        acc[ri][ci] = __builtin_amdgcn_mfma_f32_16x16x32_bf16(af[ri], bfr[ci], acc[ri][ci], 0, 0, 0);
    if (ktn < NK) {
      if (nstageA) *(uint4*)(&sA[nxt][loA]) = pa;
#pragma unroll
      for (int h = 0; h < 4; ++h) *(uint4*)(&sB[nxt][loA + h * 2048]) = pb[h];
    }
    __syncthreads();
  }

  // C/D layout: col = col0 + wn*64 + ci*16 + l16; row = rows0 + ri*16 + quad*4 + i
  if (MODE == 0) {
#pragma unroll
    for (int ri = 0; ri < 4; ++ri)
#pragma unroll
      for (int ci = 0; ci < 4; ++ci) {
        int col = col0 + wn * 64 + ci * 16 + l16;
        float bs = bias[col], gw = gnw[col], gb = gnb[col];
#pragma unroll
        for (int i = 0; i < 4; ++i) {
          float v = acc[ri][ci][i] + bs;
          float s = v;
          s += __shfl_xor(s, 1, 64); s += __shfl_xor(s, 2, 64); s += __shfl_xor(s, 4, 64);
          float mu = s * 0.125f, d = v - mu;
          float q = d * d;
          q += __shfl_xor(q, 1, 64); q += __shfl_xor(q, 2, 64); q += __shfl_xor(q, 4, 64);
          float r = d * rsqrtf(q * 0.125f + 1e-5f) * gw + gb;
          r = (r > 0.f) ? r : (__expf(r) - 1.f);
          outB[(size_t)(rows0 + ri * 16 + quad * 4 + i) * 256 + col] = f2b(r);
        }
      }
  } else if (MODE == 1) {
#pragma unroll
    for (int ri = 0; ri < 4; ++ri) {
      float ps[4] = {0.f, 0.f, 0.f, 0.f}, pd[4] = {0.f, 0.f, 0.f, 0.f};
#pragma unroll
      for (int ci = 0; ci < 4; ++ci) {
        int col = col0 + wn * 64 + ci * 16 + l16;
        float wsv = avs[col], wdv = avd[col];
#pragma unroll
        for (int i = 0; i < 4; ++i) {
          float v = acc[ri][ci][i];
          outB[(size_t)(rows0 + ri * 16 + quad * 4 + i) * 256 + col] = f2b(v);
          ps[i] += v * wsv; pd[i] += v * wdv;
        }
      }
#pragma unroll
      for (int i = 0; i < 4; ++i) {
        ps[i] += __shfl_xor(ps[i], 1, 64); ps[i] += __shfl_xor(ps[i], 2, 64);
        ps[i] += __shfl_xor(ps[i], 4, 64); ps[i] += __shfl_xor(ps[i], 8, 64);
        pd[i] += __shfl_xor(pd[i], 1, 64); pd[i] += __shfl_xor(pd[i], 2, 64);
        pd[i] += __shfl_xor(pd[i], 4, 64); pd[i] += __shfl_xor(pd[i], 8, 64);
        if (l16 == 0) {
          int r = ri * 16 + quad * 4 + i;
          sRed[0][r][wn] = ps[i];
          sRed[1][r][wn] = pd[i];
        }
      }
    }
    __syncthreads();
    if (tid < 128) {
      int arr = tid >> 6, r = tid & 63;
      float v = sRed[arr][r][0] + sRed[arr][r][1] + sRed[arr][r][2] + sRed[arr][r][3];
      (arr ? adst : asrc)[rows0 + r] = v;
    }
  } else {
#pragma unroll
    for (int ri = 0; ri < 4; ++ri)
#pragma unroll
      for (int ci = 0; ci < 4; ++ci) {
        int col = col0 + wn * 64 + ci * 16 + l16;
        float bs = bias[col] + bias2[col];
#pragma unroll
        for (int i = 0; i < 4; ++i) {
          int row = rows0 + ri * 16 + quad * 4 + i;
          if (row < Mreal) outF[(size_t)row * Nc + col] = acc[ri][ci][i] + bs;
        }
      }
  }
}

// ---------------- CSR build ----------------
__global__ void zero_k(int* p, int n) {
  int i = blockIdx.x * blockDim.x + threadIdx.x;
  if (i < n) p[i] = 0;
}

__global__ void count_deg_k(const int* __restrict__ ei, int E, int NN, int* __restrict__ counts) {
  int e = blockIdx.x * blockDim.x + threadIdx.x;
  if (e >= E + NN) return;
  int d = (e < E) ? ei[E + e] : (e - E);
  if ((unsigned)d >= (unsigned)NN) d = 0;
  atomicAdd(&counts[d], 1);
}

__global__ __launch_bounds__(1024) void scan_blk_k(const int* __restrict__ counts,
                                                   int* __restrict__ indptr,
                                                   int* __restrict__ bsums, int NN) {
  __shared__ int wsum[16];
  int t = threadIdx.x, idx = blockIdx.x * 1024 + t;
  int lane = t & 63, wid = t >> 6;
  int v = (idx < NN) ? counts[idx] : 0;
  int s = v;
#pragma unroll
  for (int off = 1; off < 64; off <<= 1) {
    int u = __shfl_up(s, off, 64);
    if (lane >= off) s += u;
  }
  if (lane == 63) wsum[wid] = s;
  __syncthreads();
  if (t == 0) {
    int run = 0;
#pragma unroll
    for (int i = 0; i < 16; i++) { int u = wsum[i]; wsum[i] = run; run += u; }
    bsums[blockIdx.x] = run;
  }
  __syncthreads();
  if (idx < NN) indptr[idx] = s - v + wsum[wid];
}

__global__ void scan_top_k(int* bsums, int nb) {
  if (threadIdx.x == 0) {
    int run = 0;
    for (int i = 0; i < nb; i++) { int t = bsums[i]; bsums[i] = run; run += t; }
  }
}

__global__ __launch_bounds__(1024) void scan_add_k(int* __restrict__ indptr, int* __restrict__ fill,
                                                   const int* __restrict__ bsums, int NN, int ET) {
  int idx = blockIdx.x * 1024 + threadIdx.x;
  if (idx < NN) {
    int v = indptr[idx] + bsums[blockIdx.x];
    indptr[idx] = v; fill[idx] = v;
  }
  if (idx == 0) indptr[NN] = ET;
}

__global__ void fill_csr_k(const int* __restrict__ ei, int E, int NN,
                           int* __restrict__ fill, int* __restrict__ csr, int ET) {
  int e = blockIdx.x * blockDim.x + threadIdx.x;
  if (e >= E + NN) return;
  int s, d;
  if (e < E) { s = ei[e]; d = ei[E + e]; } else { s = e - E; d = e - E; }
  if ((unsigned)d >= (unsigned)NN) d = 0;
  if ((unsigned)s >= (unsigned)NN) s = 0;
  int slot = atomicAdd(&fill[d], 1);
  if ((unsigned)slot < (unsigned)ET) csr[slot] = s;
}

// ---------------- GAT agg: wave/node, no-max softmax, 16B/lane 2-edge gather ----------------
__global__ __launch_bounds__(256) void gat_agg_gn_k(
    const __hip_bfloat16* __restrict__ h, const float* __restrict__ asrc,
    const float* __restrict__ adst, const int* __restrict__ indptr,
    const int* __restrict__ csr, const float* __restrict__ gbias,
    const float* __restrict__ gnw, const float* __restrict__ gnb,
    __hip_bfloat16* __restrict__ outp, int NN, int ET) {
  int n = blockIdx.x * 4 + (threadIdx.x >> 6);
  if (n >= NN) return;
  int lane = threadIdx.x & 63;
  int half = lane >> 5, l32 = lane & 31;
  int beg = indptr[n], end = indptr[n + 1];
  beg = max(0, min(beg, ET));
  end = max(beg, min(end, ET));
  int deg = end - beg;
  float adn = adst[n];
  float a[8] = {0.f, 0.f, 0.f, 0.f, 0.f, 0.f, 0.f, 0.f};
  float lw = 0.f;

  for (int cb = 0; cb < deg; cb += 64) {
    int j = cb + lane;
    int sid = 0; float w = 0.f;
    if (j < deg) {
      sid = csr[beg + j];
      if ((unsigned)sid >= (unsigned)NN) sid = 0;
      float e = asrc[sid] + adn;
      e = (e > 0.f) ? e : 0.2f * e;                  // leaky_relu 0.2
      e = fminf(fmaxf(e, -60.f), 60.f);              // softmax shift-invariant; clamp
      w = __expf(e);
    }
    lw += w;
    int cnt = min(64, deg - cb);
    for (int t = 0; t < cnt; t += 2) {
      int idx = t + half;                            // half-wave per edge; w=0 pads odd tail
      int s = __shfl(sid, idx, 64);
      float wt = __shfl(w, idx, 64);
      uint4 u = *(const uint4*)(h + (size_t)s * 256 + l32 * 8);
      a[0] += wt * bits2f(u.x & 0xffffu); a[1] += wt * bits2f(u.x >> 16);
      a[2] += wt * bits2f(u.y & 0xffffu); a[3] += wt * bits2f(u.y >> 16);
      a[4] += wt * bits2f(u.z & 0xffffu); a[5] += wt * bits2f(u.z >> 16);
      a[6] += wt * bits2f(u.w & 0xffffu); a[7] += wt * bits2f(u.w >> 16);
    }
  }
#pragma unroll
  for (int i = 0; i < 8; ++i) a[i] += __shfl_xor(a[i], 32, 64);
#pragma unroll
  for (int m = 32; m >= 1; m >>= 1) lw += __shfl_xor(lw, m, 64);
  if (half == 0) {
    float inv = 1.f / (lw + 1e-16f);
    int c0 = l32 * 8;                                // lane owns one full GN group of 8
    float v[8], mu = 0.f;
#pragma unroll
    for (int i = 0; i < 8; ++i) { v[i] = a[i] * inv + gbias[c0 + i]; mu += v[i]; }
    mu *= 0.125f;
    float q = 0.f;
#pragma unroll
    for (int i = 0; i < 8; ++i) { float d = v[i] - mu; q += d * d; }
    float rs = rsqrtf(q * 0.125f + 1e-5f);
    union { uint4 u; __hip_bfloat16 b[8]; } st;
#pragma unroll
    for (int i = 0; i < 8; ++i) {
      float r = (v[i] - mu) * rs * gnw[c0 + i] + gnb[c0 + i];
      r = (r > 0.f) ? r : (__expf(r) - 1.f);
      st.b[i] = f2b(r);
    }
    *(uint4*)(outp + (size_t)n * 256 + c0) = st.u;
  }
}

// ---------------- launch ----------------
extern "C" void kernel_launch(void* const* d_in, const int* in_sizes, int n_in,
                              void* d_out, int out_size, void* d_ws, size_t ws_size,
                              hipStream_t stream) {
  const float* x      = (const float*)d_in[0];
  const int*   ei     = (const int*)d_in[1];
  const float* pre_w  = (const float*)d_in[2];
  const float* pre_b  = (const float*)d_in[3];
  const float* lin1_b = (const float*)d_in[5];
  const float* n1_w   = (const float*)d_in[6];
  const float* n1_b   = (const float*)d_in[7];
  const float* g1_as  = (const float*)d_in[9];
  const float* g1_ad  = (const float*)d_in[10];
  const float* g1_b   = (const float*)d_in[11];
  const float* n2_w   = (const float*)d_in[12];
  const float* n2_b   = (const float*)d_in[13];
  const float* g2_as  = (const float*)d_in[15];
  const float* g2_ad  = (const float*)d_in[16];
  const float* g2_b   = (const float*)d_in[17];
  const float* n3_w   = (const float*)d_in[18];
  const float* n3_b   = (const float*)d_in[19];
  const float* lin2_b = (const float*)d_in[21];
  const float* skip_b = (const float*)d_in[23];
  float* out = (float*)d_out;

  const int C_IN  = in_sizes[2];          // 256
  const int NN    = in_sizes[0] / C_IN;   // 40000
  const int E     = in_sizes[1] / 2;      // 640000
  const int ET    = E + NN;
  const int C_OUT = in_sizes[21];         // 512
  const int NP    = (NN + 127) & ~127;    // 40064

  __hip_bfloat16* D0 = (__hip_bfloat16*)d_out;        // bf16 scratch in d_out
  __hip_bfloat16* D1 = D0 + (size_t)NP * 256;

  char* basep = (char*)d_ws;
  size_t o = 0;
  auto alloc = [&](size_t bytes) { size_t r = o; o += (bytes + 255) & ~(size_t)255; return r; };
  __hip_bfloat16* Y      = (__hip_bfloat16*)(basep + alloc((size_t)NP * 256 * 2));
  __hip_bfloat16* Wcat   = (__hip_bfloat16*)(basep + alloc((size_t)458752 * 2));
  float*          asrc   = (float*)(basep + alloc((size_t)NP * 4));
  float*          adst   = (float*)(basep + alloc((size_t)NP * 4));
  int*            indptr = (int*)(basep + alloc((size_t)(NN + 1) * 4));
  int*            counts = (int*)(basep + alloc((size_t)NN * 4));
  int*            fill   = (int*)(basep + alloc((size_t)NN * 4));
  int*            bsums  = (int*)(basep + alloc(256));
  int*            csr    = (int*)(basep + alloc((size_t)ET * 4));
  size_t base_need = o;
  size_t xb_need = ((size_t)NP * 256 * 2 + 255) & ~(size_t)255;
  const bool use_xb = (ws_size >= base_need + xb_need);
  __hip_bfloat16* xb = use_xb ? (__hip_bfloat16*)(basep + alloc(xb_need)) : nullptr;

  __hip_bfloat16* Wlin1 = Wcat;
  __hip_bfloat16* Wg1   = Wcat + 65536;
  __hip_bfloat16* Wg2   = Wcat + 131072;
  __hip_bfloat16* Wlin2 = Wcat + 196608;
  __hip_bfloat16* Wskip = Wcat + 327680;

  dim3 blk(256);
  const int nb = (NN + 1023) / 1024;      // 40

  conv_w_k<<<(458752 / 4 + 255) / 256, blk, 0, stream>>>(
      (const float*)d_in[4], (const float*)d_in[8], (const float*)d_in[14],
      (const float*)d_in[20], (const float*)d_in[22], Wcat);
  zero_k<<<(NN + 255) / 256, blk, 0, stream>>>(counts, NN);
  count_deg_k<<<(ET + 255) / 256, blk, 0, stream>>>(ei, E, NN, counts);
  scan_blk_k<<<nb, 1024, 0, stream>>>(counts, indptr, bsums, NN);
  scan_top_k<<<1, 64, 0, stream>>>(bsums, nb);
  scan_add_k<<<nb, 1024, 0, stream>>>(indptr, fill, bsums, NN, ET);
  fill_csr_k<<<(ET + 255) / 256, blk, 0, stream>>>(ei, E, NN, fill, csr, ET);

  gn_elu_k<<<(NN * 32 + 255) / 256, blk, 0, stream>>>(x, pre_w, pre_b, D0, xb, NN * 32);
  // lin1 + GN1 + ELU
  gemm_t<0><<<dim3(1, NP / 64), blk, 0, stream>>>(D0, nullptr, nullptr, Wlin1, nullptr,
      lin1_b, nullptr, n1_w, n1_b, nullptr, nullptr, Y, nullptr, nullptr, nullptr, 256, NN);
  // GAT1
  gemm_t<1><<<dim3(1, NP / 64), blk, 0, stream>>>(Y, nullptr, nullptr, Wg1, nullptr,
      nullptr, nullptr, nullptr, nullptr, g1_as, g1_ad, D0, nullptr, asrc, adst, 256, NN);
  gat_agg_gn_k<<<NN / 4, blk, 0, stream>>>(D0, asrc, adst, indptr, csr, g1_b, n2_w, n2_b, D1, NN, ET);
  // GAT2
  gemm_t<1><<<dim3(1, NP / 64), blk, 0, stream>>>(D1, nullptr, nullptr, Wg2, nullptr,
      nullptr, nullptr, nullptr, nullptr, g2_as, g2_ad, D0, nullptr, asrc, adst, 256, NN);
  gat_agg_gn_k<<<NN / 4, blk, 0, stream>>>(D0, asrc, adst, indptr, csr, g2_b, n3_w, n3_b, Y, NN, ET);
  // lin2 + skip fused -> out (K=512)
  if (use_xb) {
    gemm_t<2><<<dim3(C_OUT / 256, NP / 64), blk, 0, stream>>>(Y, xb, nullptr, Wlin2, Wskip,
        lin2_b, skip_b, nullptr, nullptr, nullptr, nullptr, nullptr, out, nullptr, nullptr, C_OUT, NN);
  } else {
    gemm_t<3><<<dim3(C_OUT / 256, NP / 64), blk, 0, stream>>>(Y, nullptr, x, Wlin2, Wskip,
        lin2_b, skip_b, nullptr, nullptr, nullptr, nullptr, nullptr, out, nullptr, nullptr, C_OUT, NN);
  }
}